// Round 4
// baseline (880.178 us; speedup 1.0000x reference)
//
#include <hip/hip_runtime.h>
#include <cstdint>

typedef __attribute__((ext_vector_type(8))) short bf16x8;
typedef __attribute__((ext_vector_type(4))) float f32x4;

__device__ __forceinline__ unsigned short f2bf(float v) {
  unsigned u = __builtin_bit_cast(unsigned, v);
  u += 0x7FFFu + ((u >> 16) & 1u);   // RNE
  return (unsigned short)(u >> 16);
}

// async global->LDS, 16B per lane; LDS dest = wave-uniform base + lane*16
__device__ __forceinline__ void gload16(const unsigned short* g, unsigned short* l) {
  __builtin_amdgcn_global_load_lds(
      (const __attribute__((address_space(1))) void*)(uintptr_t)g,
      (__attribute__((address_space(3))) void*)(uint32_t)(uintptr_t)l,
      16, 0, 0);
}

// Pipelined bf16 NT GEMM core: C[128x128] += A[128xK] * B[128xK]^T, BK=64.
// B: double-buffered LDS (XOR-swizzled, conflict-free), staged via
//    global_load_lds; ONE barrier per K-iteration.
// A: never touches LDS -- per-wave fragments loaded global->VGPR, double
//    buffered, issued one iteration ahead so the load latency overlaps the
//    MFMAs (the AITER-style loads-in-flight-across-the-barrier pattern).
__device__ __forceinline__ void gemm_core(
    const unsigned short* __restrict__ A, const unsigned short* __restrict__ B,
    int lda, int ldb, int K,
    unsigned short* ldsB, f32x4 acc[4][4])
{
  const int tid  = threadIdx.x;
  const int wave = tid >> 6;
  const int lane = tid & 63;
  const int wm = (wave >> 1) * 64;
  const int wn = (wave & 1) * 64;
  const int lrow = lane & 15;
  const int kq = lane >> 4;

  // B staging: wave w fills rows [w*32, w*32+32); row = w*32 + i*8 + sr,
  // physical chunk (lane&7) holds logical chunk (lane&7)^(sr&7).
  const int sr = lane >> 3;
  const int sc = (lane & 7) ^ (sr & 7);
  const unsigned short* gb = B + (long)(wave * 32 + sr) * ldb + sc * 8;
  unsigned short* lB = ldsB + wave * 2048;   // within-buffer slice

  // A fragments: frag(i,ks) = rows wm+i*16+lrow, cols kb+(ks*4+kq)*8
  const unsigned short* gaBase = A + (long)(wm + lrow) * lda + kq * 8;

  // read-side swizzle: logical chunk (ks*4+kq) of row lrow at physical ^(lrow&7)
  const int pc0 = ((0 + kq) ^ (lrow & 7)) * 8;
  const int pc1 = ((4 + kq) ^ (lrow & 7)) * 8;

  bf16x8 ar[2][8];

  // prologue: stage B(0) -> buf0, prefetch A(0) -> ar[0]
#pragma unroll
  for (int i = 0; i < 4; ++i)
    gload16(gb + (long)i * 8 * ldb, lB + i * 512);
#pragma unroll
  for (int i = 0; i < 4; ++i) {
    ar[0][i * 2 + 0] = *(const bf16x8*)(gaBase + (long)(i * 16) * lda);
    ar[0][i * 2 + 1] = *(const bf16x8*)(gaBase + (long)(i * 16) * lda + 32);
  }
  __syncthreads();   // B(0) staged, A(0) landed

  const int nIter = K >> 6;
#pragma unroll 1
  for (int it = 0; it < nIter; ++it) {
    const int cur = it & 1;
    const unsigned short* bufC = ldsB + cur * 8192;

    // issue next iteration's loads FIRST so they fly during the MFMAs
    if (it + 1 < nIter) {
      const long kb2 = (long)(it + 1) << 6;
      unsigned short* bufN = lB + (cur ^ 1) * 8192;
#pragma unroll
      for (int i = 0; i < 4; ++i)
        gload16(gb + kb2 + (long)i * 8 * ldb, bufN + i * 512);
#pragma unroll
      for (int i = 0; i < 4; ++i) {
        ar[cur ^ 1][i * 2 + 0] = *(const bf16x8*)(gaBase + kb2 + (long)(i * 16) * lda);
        ar[cur ^ 1][i * 2 + 1] = *(const bf16x8*)(gaBase + kb2 + (long)(i * 16) * lda + 32);
      }
    }

    bf16x8 bfr[4];
    // k-step 0
#pragma unroll
    for (int j = 0; j < 4; ++j)
      bfr[j] = *(const bf16x8*)(bufC + (wn + j * 16 + lrow) * 64 + pc0);
#pragma unroll
    for (int i = 0; i < 4; ++i)
#pragma unroll
      for (int j = 0; j < 4; ++j)
        acc[i][j] = __builtin_amdgcn_mfma_f32_16x16x32_bf16(ar[cur][i * 2], bfr[j], acc[i][j], 0, 0, 0);
    // k-step 1
#pragma unroll
    for (int j = 0; j < 4; ++j)
      bfr[j] = *(const bf16x8*)(bufC + (wn + j * 16 + lrow) * 64 + pc1);
#pragma unroll
    for (int i = 0; i < 4; ++i)
#pragma unroll
      for (int j = 0; j < 4; ++j)
        acc[i][j] = __builtin_amdgcn_mfma_f32_16x16x32_bf16(ar[cur][i * 2 + 1], bfr[j], acc[i][j], 0, 0, 0);

    // one barrier: guarantees buf(cur^1) staged AND buf(cur) fully consumed
    __syncthreads();
  }
}

// QKV projection: x[8192,1024] * W[1024,1024]^T + b, fused over Q/K/V via blockIdx.y.
// Q,K stored row-major bf16; V stored transposed per batch: Vt[b][d][m].
__global__ __launch_bounds__(256, 3) void gemm_qkv(
    const unsigned short* __restrict__ xh,
    const unsigned short* __restrict__ wh,
    const float* __restrict__ bq, const float* __restrict__ bk, const float* __restrict__ bv,
    unsigned short* __restrict__ Qh, unsigned short* __restrict__ Kh,
    unsigned short* __restrict__ Vth)
{
  __shared__ __align__(16) unsigned short ldsB[16384];   // 32 KB, double buffer
  const int Mblk = blockIdx.x * 128;
  const int sel  = blockIdx.y >> 3;   // 0=Q 1=K 2=V
  const int nb   = blockIdx.y & 7;    // 128-wide col block within 1024

  const unsigned short* A = xh + (long)Mblk * 1024;
  const unsigned short* B = wh + sel * 1048576 + (long)(nb * 128) * 1024;
  const float* bias = (sel == 0) ? bq : (sel == 1) ? bk : bv;

  f32x4 acc[4][4] = {};
  gemm_core(A, B, 1024, 1024, 1024, ldsB, acc);

  const int lane = threadIdx.x & 63, wave = threadIdx.x >> 6;
  const int wm = (wave >> 1) * 64, wn = (wave & 1) * 64;
  const int lrow = lane & 15, kq = lane >> 4;

#pragma unroll
  for (int i = 0; i < 4; ++i) {
#pragma unroll
    for (int j = 0; j < 4; ++j) {
      const int col = nb * 128 + wn + j * 16 + lrow;   // output feature d
      const float bsv = bias[col];
#pragma unroll
      for (int r = 0; r < 4; ++r) {
        const int tok = Mblk + wm + i * 16 + kq * 4 + r;  // token index
        const unsigned short h = f2bf(acc[i][j][r] + bsv);
        if (sel == 2) {
          Vth[(long)(tok >> 11) * 2097152 + (long)col * 2048 + (tok & 2047)] = h;
        } else if (sel == 0) {
          Qh[(long)tok * 1024 + col] = h;
        } else {
          Kh[(long)tok * 1024 + col] = h;
        }
      }
    }
  }
}

// Batched NT GEMM with fp32 output: C[z] = alpha * A[z] * B[z]^T
__global__ __launch_bounds__(256, 3) void gemm_f32out(
    const unsigned short* __restrict__ A, const unsigned short* __restrict__ B,
    int lda, int ldb, int K,
    long sA, long sB, float* __restrict__ C, int ldc, long sC, float alpha)
{
  __shared__ __align__(16) unsigned short ldsB[16384];
  const int Mblk = blockIdx.x * 128;
  const int Nblk = blockIdx.y * 128;
  const long z = blockIdx.z;
  const unsigned short* Ab = A + z * sA + (long)Mblk * lda;
  const unsigned short* Bb = B + z * sB + (long)Nblk * ldb;
  float* Cb = C + z * sC;

  f32x4 acc[4][4] = {};
  gemm_core(Ab, Bb, lda, ldb, K, ldsB, acc);

  const int lane = threadIdx.x & 63, wave = threadIdx.x >> 6;
  const int wm = (wave >> 1) * 64, wn = (wave & 1) * 64;
  const int lrow = lane & 15, kq = lane >> 4;
#pragma unroll
  for (int i = 0; i < 4; ++i)
#pragma unroll
    for (int j = 0; j < 4; ++j)
#pragma unroll
      for (int r = 0; r < 4; ++r) {
        const int row = Mblk + wm + i * 16 + kq * 4 + r;
        const int col = Nblk + wn + j * 16 + lrow;
        Cb[(long)row * ldc + col] = alpha * acc[i][j][r];
      }
}

// Row softmax over 2048 entries, in place (fp32) + bf16 copy for the PV GEMM.
__global__ __launch_bounds__(256) void softmax_rows(
    float* __restrict__ S, unsigned short* __restrict__ Ph)
{
  __shared__ float red[4];
  const long row = blockIdx.x;
  float* rp = S + row * 2048;
  const int t = threadIdx.x;

  float x[8];
  *(float4*)&x[0] = reinterpret_cast<const float4*>(rp)[t];
  *(float4*)&x[4] = reinterpret_cast<const float4*>(rp)[t + 256];

  float m = x[0];
#pragma unroll
  for (int i = 1; i < 8; ++i) m = fmaxf(m, x[i]);
  for (int o = 32; o; o >>= 1) m = fmaxf(m, __shfl_xor(m, o, 64));
  if ((t & 63) == 0) red[t >> 6] = m;
  __syncthreads();
  m = fmaxf(fmaxf(red[0], red[1]), fmaxf(red[2], red[3]));
  __syncthreads();

  float s = 0.f;
#pragma unroll
  for (int i = 0; i < 8; ++i) { x[i] = expf(x[i] - m); s += x[i]; }
  for (int o = 32; o; o >>= 1) s += __shfl_xor(s, o, 64);
  if ((t & 63) == 0) red[t >> 6] = s;
  __syncthreads();
  s = (red[0] + red[1]) + (red[2] + red[3]);
  const float inv = 1.0f / s;

#pragma unroll
  for (int i = 0; i < 8; ++i) x[i] *= inv;
  reinterpret_cast<float4*>(rp)[t]       = *(float4*)&x[0];
  reinterpret_cast<float4*>(rp)[t + 256] = *(float4*)&x[4];

  const long b0 = row * 2048 + t * 4;
#pragma unroll
  for (int k = 0; k < 4; ++k) Ph[b0 + k] = f2bf(x[k]);
  const long b1 = row * 2048 + 1024 + t * 4;
#pragma unroll
  for (int k = 0; k < 4; ++k) Ph[b1 + k] = f2bf(x[4 + k]);
}

__global__ __launch_bounds__(256) void to_bf16(
    const float* __restrict__ x, unsigned short* __restrict__ hi, int n)
{
  int i = blockIdx.x * 256 + threadIdx.x;
  const int stride = gridDim.x * 256;
  for (; i < n; i += stride) hi[i] = f2bf(x[i]);
}

extern "C" void kernel_launch(void* const* d_in, const int* in_sizes, int n_in,
                              void* d_out, int out_size, void* d_ws, size_t ws_size,
                              hipStream_t stream)
{
  const float* x  = (const float*)d_in[0];
  const float* Wq = (const float*)d_in[1];
  const float* bq = (const float*)d_in[2];
  const float* Wk = (const float*)d_in[3];
  const float* bk = (const float*)d_in[4];
  const float* Wv = (const float*)d_in[5];
  const float* bv = (const float*)d_in[6];

  float* out  = (float*)d_out;                 // [4,2048,1024]
  float* attn = (float*)d_out + 8388608;       // [4,2048,2048]

  unsigned short* ws  = (unsigned short*)d_ws;
  unsigned short* xh  = ws;                    //  8,388,608
  unsigned short* wh  = xh + 8388608;          //  3,145,728 (Wq|Wk|Wv)
  unsigned short* Qh  = wh + 3145728;          //  8,388,608
  unsigned short* Kh  = Qh + 8388608;          //  8,388,608
  unsigned short* Vth = Kh + 8388608;          //  8,388,608  Vt[b][d][m]
  unsigned short* Ph  = Vth + 8388608;         // 16,777,216  P bf16

  to_bf16<<<4096, 256, 0, stream>>>(x, xh, 8388608);
  to_bf16<<<512, 256, 0, stream>>>(Wq, wh, 1048576);
  to_bf16<<<512, 256, 0, stream>>>(Wk, wh + 1048576, 1048576);
  to_bf16<<<512, 256, 0, stream>>>(Wv, wh + 2097152, 1048576);

  // Q,K,V projections (M=8192, N=3x1024, K=1024)
  gemm_qkv<<<dim3(64, 24), 256, 0, stream>>>(xh, wh, bq, bk, bv, Qh, Kh, Vth);

  // scores = Q K^T / 32  -> fp32 straight into d_out's attention slot
  gemm_f32out<<<dim3(16, 16, 4), 256, 0, stream>>>(Qh, Kh, 1024, 1024, 1024,
      2097152L, 2097152L, attn, 2048, 4194304L, 0.03125f);

  // softmax rows in place + emit P bf16
  softmax_rows<<<8192, 256, 0, stream>>>(attn, Ph);

  // out = P * Vt^T
  gemm_f32out<<<dim3(16, 8, 4), 256, 0, stream>>>(Ph, Vth, 2048, 2048, 2048,
      4194304L, 2097152L, out, 1024, 2097152L, 1.0f);
}

// Round 5
// 479.040 us; speedup vs baseline: 1.8374x; 1.8374x over previous
//
#include <hip/hip_runtime.h>
#include <cstdint>

typedef __attribute__((ext_vector_type(8))) short bf16x8;
typedef __attribute__((ext_vector_type(4))) float f32x4;

__device__ __forceinline__ unsigned short f2bf(float v) {
  unsigned u = __builtin_bit_cast(unsigned, v);
  u += 0x7FFFu + ((u >> 16) & 1u);   // RNE
  return (unsigned short)(u >> 16);
}

// async global->LDS, 16B per lane; LDS dest = wave-uniform base + lane*16
__device__ __forceinline__ void gload16(const unsigned short* g, unsigned short* l) {
  __builtin_amdgcn_global_load_lds(
      (const __attribute__((address_space(1))) void*)(uintptr_t)g,
      (__attribute__((address_space(3))) void*)(uint32_t)(uintptr_t)l,
      16, 0, 0);
}

// Pipelined bf16 NT GEMM core: C[128x128] += A[128xK] * B[128xK]^T, BK=64.
// B: double-buffered LDS (XOR-swizzled, conflict-free), staged via
//    global_load_lds, one barrier per K-step. A: global->VGPR, double
//    buffered. K-loop unrolled x2 so ALL buffer indices are compile-time
//    constants (dynamic indexing of the reg array caused scratch spills in
//    round 4: WRITE_SIZE 51->843 MB).
__device__ __forceinline__ void compute_step(
    const unsigned short* __restrict__ bufC, const bf16x8 (&ar)[8],
    f32x4 acc[4][4], int wn, int lrow, int pc0, int pc1)
{
  bf16x8 bfr[4];
#pragma unroll
  for (int j = 0; j < 4; ++j)
    bfr[j] = *(const bf16x8*)(bufC + (wn + j * 16 + lrow) * 64 + pc0);
#pragma unroll
  for (int i = 0; i < 4; ++i)
#pragma unroll
    for (int j = 0; j < 4; ++j)
      acc[i][j] = __builtin_amdgcn_mfma_f32_16x16x32_bf16(ar[i * 2], bfr[j], acc[i][j], 0, 0, 0);
#pragma unroll
  for (int j = 0; j < 4; ++j)
    bfr[j] = *(const bf16x8*)(bufC + (wn + j * 16 + lrow) * 64 + pc1);
#pragma unroll
  for (int i = 0; i < 4; ++i)
#pragma unroll
    for (int j = 0; j < 4; ++j)
      acc[i][j] = __builtin_amdgcn_mfma_f32_16x16x32_bf16(ar[i * 2 + 1], bfr[j], acc[i][j], 0, 0, 0);
}

__device__ __forceinline__ void gemm_core(
    const unsigned short* __restrict__ A, const unsigned short* __restrict__ B,
    int lda, int ldb, int K,
    unsigned short* ldsB, f32x4 acc[4][4])
{
  const int tid  = threadIdx.x;
  const int wave = tid >> 6;
  const int lane = tid & 63;
  const int wm = (wave >> 1) * 64;
  const int wn = (wave & 1) * 64;
  const int lrow = lane & 15;
  const int kq = lane >> 4;

  // B staging: wave w fills rows [w*32, w*32+32); row = w*32 + i*8 + sr,
  // physical chunk (lane&7) holds logical chunk (lane&7)^(sr&7).
  const int sr = lane >> 3;
  const int sc = (lane & 7) ^ (sr & 7);
  const unsigned short* gb = B + (long)(wave * 32 + sr) * ldb + sc * 8;
  unsigned short* lB = ldsB + wave * 2048;   // staging slice within buffer 0

  // A fragments: frag(i,ks) = rows wm+i*16+lrow, cols kb+(ks*4+kq)*8
  const unsigned short* gaBase = A + (long)(wm + lrow) * lda + kq * 8;

  // read-side swizzle: logical chunk (ks*4+kq) of row lrow at physical ^(lrow&7)
  const int pc0 = ((0 + kq) ^ (lrow & 7)) * 8;
  const int pc1 = ((4 + kq) ^ (lrow & 7)) * 8;

  bf16x8 ar0[8], ar1[8];

#define STAGE_B(kb, bufOfs)                                          \
  {                                                                  \
    _Pragma("unroll")                                                \
    for (int i = 0; i < 4; ++i)                                      \
      gload16(gb + (kb) + (long)i * 8 * ldb, lB + (bufOfs) + i * 512); \
  }
#define PREF_A(kb, ar)                                               \
  {                                                                  \
    _Pragma("unroll")                                                \
    for (int i = 0; i < 4; ++i) {                                    \
      ar[i * 2 + 0] = *(const bf16x8*)(gaBase + (kb) + (long)(i * 16) * lda);      \
      ar[i * 2 + 1] = *(const bf16x8*)(gaBase + (kb) + (long)(i * 16) * lda + 32); \
    }                                                                \
  }

  // prologue: stage B(0) -> buf0, prefetch A(0) -> ar0
  STAGE_B(0L, 0)
  PREF_A(0L, ar0)
  __syncthreads();

  const int nIter = K >> 6;   // even (16 or 32)
#pragma unroll 1
  for (int it = 0; it < nIter; it += 2) {
    const long kb1 = (long)(it + 1) << 6;
    STAGE_B(kb1, 8192)        // B(it+1) -> buf1 (it+1 < nIter always: nIter even)
    PREF_A(kb1, ar1)
    compute_step(ldsB, ar0, acc, wn, lrow, pc0, pc1);
    __syncthreads();          // buf1 staged AND buf0 consumed

    if (it + 2 < nIter) {
      const long kb2 = (long)(it + 2) << 6;
      STAGE_B(kb2, 0)         // B(it+2) -> buf0
      PREF_A(kb2, ar0)
    }
    compute_step(ldsB + 8192, ar1, acc, wn, lrow, pc0, pc1);
    __syncthreads();          // buf0 staged AND buf1 consumed
  }
#undef STAGE_B
#undef PREF_A
}

// QKV projection: x[8192,1024] * W[1024,1024]^T + b, fused over Q/K/V via blockIdx.y.
// Q,K stored row-major bf16; V stored transposed per batch: Vt[b][d][m].
__global__ __launch_bounds__(256, 3) void gemm_qkv(
    const unsigned short* __restrict__ xh,
    const unsigned short* __restrict__ wh,
    const float* __restrict__ bq, const float* __restrict__ bk, const float* __restrict__ bv,
    unsigned short* __restrict__ Qh, unsigned short* __restrict__ Kh,
    unsigned short* __restrict__ Vth)
{
  __shared__ __align__(16) unsigned short ldsB[16384];   // 32 KB, double buffer
  const int Mblk = blockIdx.x * 128;
  const int sel  = blockIdx.y >> 3;   // 0=Q 1=K 2=V
  const int nb   = blockIdx.y & 7;    // 128-wide col block within 1024

  const unsigned short* A = xh + (long)Mblk * 1024;
  const unsigned short* B = wh + sel * 1048576 + (long)(nb * 128) * 1024;
  const float* bias = (sel == 0) ? bq : (sel == 1) ? bk : bv;

  f32x4 acc[4][4] = {};
  gemm_core(A, B, 1024, 1024, 1024, ldsB, acc);

  const int lane = threadIdx.x & 63, wave = threadIdx.x >> 6;
  const int wm = (wave >> 1) * 64, wn = (wave & 1) * 64;
  const int lrow = lane & 15, kq = lane >> 4;

#pragma unroll
  for (int i = 0; i < 4; ++i) {
#pragma unroll
    for (int j = 0; j < 4; ++j) {
      const int col = nb * 128 + wn + j * 16 + lrow;   // output feature d
      const float bsv = bias[col];
#pragma unroll
      for (int r = 0; r < 4; ++r) {
        const int tok = Mblk + wm + i * 16 + kq * 4 + r;  // token index
        const unsigned short h = f2bf(acc[i][j][r] + bsv);
        if (sel == 2) {
          Vth[(long)(tok >> 11) * 2097152 + (long)col * 2048 + (tok & 2047)] = h;
        } else if (sel == 0) {
          Qh[(long)tok * 1024 + col] = h;
        } else {
          Kh[(long)tok * 1024 + col] = h;
        }
      }
    }
  }
}

// Batched NT GEMM with fp32 output: C[z] = alpha * A[z] * B[z]^T
__global__ __launch_bounds__(256, 3) void gemm_f32out(
    const unsigned short* __restrict__ A, const unsigned short* __restrict__ B,
    int lda, int ldb, int K,
    long sA, long sB, float* __restrict__ C, int ldc, long sC, float alpha)
{
  __shared__ __align__(16) unsigned short ldsB[16384];
  const int Mblk = blockIdx.x * 128;
  const int Nblk = blockIdx.y * 128;
  const long z = blockIdx.z;
  const unsigned short* Ab = A + z * sA + (long)Mblk * lda;
  const unsigned short* Bb = B + z * sB + (long)Nblk * ldb;
  float* Cb = C + z * sC;

  f32x4 acc[4][4] = {};
  gemm_core(Ab, Bb, lda, ldb, K, ldsB, acc);

  const int lane = threadIdx.x & 63, wave = threadIdx.x >> 6;
  const int wm = (wave >> 1) * 64, wn = (wave & 1) * 64;
  const int lrow = lane & 15, kq = lane >> 4;
#pragma unroll
  for (int i = 0; i < 4; ++i)
#pragma unroll
    for (int j = 0; j < 4; ++j)
#pragma unroll
      for (int r = 0; r < 4; ++r) {
        const int row = Mblk + wm + i * 16 + kq * 4 + r;
        const int col = Nblk + wn + j * 16 + lrow;
        Cb[(long)row * ldc + col] = alpha * acc[i][j][r];
      }
}

// Row softmax over 2048 entries, in place (fp32) + bf16 copy for the PV GEMM.
__global__ __launch_bounds__(256) void softmax_rows(
    float* __restrict__ S, unsigned short* __restrict__ Ph)
{
  __shared__ float red[4];
  const long row = blockIdx.x;
  float* rp = S + row * 2048;
  const int t = threadIdx.x;

  float x[8];
  *(float4*)&x[0] = reinterpret_cast<const float4*>(rp)[t];
  *(float4*)&x[4] = reinterpret_cast<const float4*>(rp)[t + 256];

  float m = x[0];
#pragma unroll
  for (int i = 1; i < 8; ++i) m = fmaxf(m, x[i]);
  for (int o = 32; o; o >>= 1) m = fmaxf(m, __shfl_xor(m, o, 64));
  if ((t & 63) == 0) red[t >> 6] = m;
  __syncthreads();
  m = fmaxf(fmaxf(red[0], red[1]), fmaxf(red[2], red[3]));
  __syncthreads();

  float s = 0.f;
#pragma unroll
  for (int i = 0; i < 8; ++i) { x[i] = expf(x[i] - m); s += x[i]; }
  for (int o = 32; o; o >>= 1) s += __shfl_xor(s, o, 64);
  if ((t & 63) == 0) red[t >> 6] = s;
  __syncthreads();
  s = (red[0] + red[1]) + (red[2] + red[3]);
  const float inv = 1.0f / s;

#pragma unroll
  for (int i = 0; i < 8; ++i) x[i] *= inv;
  reinterpret_cast<float4*>(rp)[t]       = *(float4*)&x[0];
  reinterpret_cast<float4*>(rp)[t + 256] = *(float4*)&x[4];

  const long b0 = row * 2048 + t * 4;
#pragma unroll
  for (int k = 0; k < 4; ++k) Ph[b0 + k] = f2bf(x[k]);
  const long b1 = row * 2048 + 1024 + t * 4;
#pragma unroll
  for (int k = 0; k < 4; ++k) Ph[b1 + k] = f2bf(x[4 + k]);
}

__global__ __launch_bounds__(256) void to_bf16(
    const float* __restrict__ x, unsigned short* __restrict__ hi, int n)
{
  int i = blockIdx.x * 256 + threadIdx.x;
  const int stride = gridDim.x * 256;
  for (; i < n; i += stride) hi[i] = f2bf(x[i]);
}

extern "C" void kernel_launch(void* const* d_in, const int* in_sizes, int n_in,
                              void* d_out, int out_size, void* d_ws, size_t ws_size,
                              hipStream_t stream)
{
  const float* x  = (const float*)d_in[0];
  const float* Wq = (const float*)d_in[1];
  const float* bq = (const float*)d_in[2];
  const float* Wk = (const float*)d_in[3];
  const float* bk = (const float*)d_in[4];
  const float* Wv = (const float*)d_in[5];
  const float* bv = (const float*)d_in[6];

  float* out  = (float*)d_out;                 // [4,2048,1024]
  float* attn = (float*)d_out + 8388608;       // [4,2048,2048]

  unsigned short* ws  = (unsigned short*)d_ws;
  unsigned short* xh  = ws;                    //  8,388,608
  unsigned short* wh  = xh + 8388608;          //  3,145,728 (Wq|Wk|Wv)
  unsigned short* Qh  = wh + 3145728;          //  8,388,608
  unsigned short* Kh  = Qh + 8388608;          //  8,388,608
  unsigned short* Vth = Kh + 8388608;          //  8,388,608  Vt[b][d][m]
  unsigned short* Ph  = Vth + 8388608;         // 16,777,216  P bf16

  to_bf16<<<4096, 256, 0, stream>>>(x, xh, 8388608);
  to_bf16<<<512, 256, 0, stream>>>(Wq, wh, 1048576);
  to_bf16<<<512, 256, 0, stream>>>(Wk, wh + 1048576, 1048576);
  to_bf16<<<512, 256, 0, stream>>>(Wv, wh + 2097152, 1048576);

  // Q,K,V projections (M=8192, N=3x1024, K=1024)
  gemm_qkv<<<dim3(64, 24), 256, 0, stream>>>(xh, wh, bq, bk, bv, Qh, Kh, Vth);

  // scores = Q K^T / 32  -> fp32 straight into d_out's attention slot
  gemm_f32out<<<dim3(16, 16, 4), 256, 0, stream>>>(Qh, Kh, 1024, 1024, 1024,
      2097152L, 2097152L, attn, 2048, 4194304L, 0.03125f);

  // softmax rows in place + emit P bf16
  softmax_rows<<<8192, 256, 0, stream>>>(attn, Ph);

  // out = P * Vt^T
  gemm_f32out<<<dim3(16, 8, 4), 256, 0, stream>>>(Ph, Vth, 2048, 2048, 2048,
      4194304L, 2097152L, out, 1024, 2097152L, 1.0f);
}